// Round 6
// baseline (609.438 us; speedup 1.0000x reference)
//
#include <hip/hip_runtime.h>
#include <hip/hip_bf16.h>
#include <stdint.h>

typedef unsigned short u16;
typedef __attribute__((ext_vector_type(4))) unsigned short u16x4;
typedef __attribute__((ext_vector_type(8))) short short8;
typedef __attribute__((ext_vector_type(4))) float f32x4;

__device__ inline u16 f2b(float f) {
  uint32_t u = __builtin_bit_cast(uint32_t, f);
  u += 0x7fffu + ((u >> 16) & 1u);   // RNE round to bf16
  return (u16)(u >> 16);
}

#define BM 128
#define BN 128
#define BK 64
#define NBLK 512

__device__ inline void load_lds16(const void* g, void* l) {
  __builtin_amdgcn_global_load_lds((const __attribute__((address_space(1))) void*)g,
                                   (__attribute__((address_space(3))) void*)l, 16, 0, 0);
}

// ---- software grid barrier: per-phase counter, device-scope atomics ----
// All 512 blocks are co-resident (launch_bounds(256,2): VGPR<=256, LDS 32KB
// -> 2 blocks/CU x 256 CUs). Counters zeroed each graph replay by a memset node.
__device__ inline void gbar(int* cnt) {
  __syncthreads();
  if (threadIdx.x == 0) {
    __threadfence();                                   // release prior writes (agent)
    __hip_atomic_fetch_add(cnt, 1, __ATOMIC_ACQ_REL, __HIP_MEMORY_SCOPE_AGENT);
    while (__hip_atomic_load(cnt, __ATOMIC_ACQUIRE, __HIP_MEMORY_SCOPE_AGENT) < NBLK)
      __builtin_amdgcn_s_sleep(2);
  }
  __syncthreads();
  __threadfence();                                     // acquire side for all threads
}

// ---------------- proven 128x128 bt-GEMM tile as a device function ----------------
// C[m][n] = sum_k A[m][k] * Bt[n][k]; XOR-swizzled LDS, global_load_lds width-16.
// MODE 0: QKV epilogue (bias; cols>=2048 go pre-transposed into vtOut)
// MODE 2: scores epilogue: P = exp(v*scale + mask) bf16; rowsum[row] += partials
// MODE 4: PV epilogue: fp32, v / rowsum[row]
template <int MODE>
__device__ __forceinline__ void gemm_tile(
    u16* lA, u16* lB,
    const u16* __restrict__ A, const u16* __restrict__ Bt, void* __restrict__ C,
    u16* __restrict__ vtOut, const float* __restrict__ bias,
    float* __restrict__ rsum, const float* __restrict__ maskG,
    int K, int lda, int ldb, int ldc,
    int m0, int n0, long cbase, int z, float scale)
{
  const int t = threadIdx.x;
  const int lane = t & 63;
  const int wave = t >> 6;
  const int wr = wave >> 1, wc = wave & 1;

  // Staging: LDS [128 rows][8 chunks of 8 u16]; slot s of row r holds global
  // chunk s ^ (r&7) -> conflict-free ds_read_b128; linear LDS dest (rule 21).
  const int srow = t >> 3;
  const int schunk = (t & 7) ^ (srow & 7);
  const u16* aS = A + (long)(m0 + srow) * lda + schunk * 8;
  const u16* bS = Bt + (long)(n0 + srow) * ldb + schunk * 8;

  f32x4 acc[4][4] = {};
  const int fr = lane & 15;
  const int q4 = lane >> 4;

  for (int k0 = 0; k0 < K; k0 += BK) {
    __syncthreads();                 // prior LDS reads done before overwrite
#pragma unroll
    for (int i = 0; i < 4; i++) {
      load_lds16(aS + k0 + (long)(i * 32) * lda, &lA[(i * 256 + t) * 8]);
      load_lds16(bS + k0 + (long)(i * 32) * ldb, &lB[(i * 256 + t) * 8]);
    }
    __syncthreads();                 // drain global_load_lds
#pragma unroll
    for (int kk = 0; kk < 2; kk++) {
      const int ch = kk * 4 + q4;
      short8 aF[4], bF[4];
#pragma unroll
      for (int i = 0; i < 4; i++) {
        int row = wr * 64 + i * 16 + fr;
        aF[i] = *(const short8*)&lA[row * BK + ((ch ^ (row & 7)) * 8)];
      }
#pragma unroll
      for (int j = 0; j < 4; j++) {
        int row = wc * 64 + j * 16 + fr;
        bF[j] = *(const short8*)&lB[row * BK + ((ch ^ (row & 7)) * 8)];
      }
#pragma unroll
      for (int i = 0; i < 4; i++)
#pragma unroll
        for (int j = 0; j < 4; j++)
          acc[i][j] = __builtin_amdgcn_mfma_f32_16x16x32_bf16(aF[i], bF[j], acc[i][j], 0, 0, 0);
    }
  }

  // epilogue: C/D layout col = lane&15, row = (lane>>4)*4 + r
  const int r0 = q4 * 4;
  if (MODE == 2) {
    const float* mk = maskG + (long)z * 2048 * 2048;
    u16* Pout = (u16*)C + cbase;
    float* rz = rsum + (long)z * 2048;
#pragma unroll
    for (int i = 0; i < 4; i++) {
      const int row = m0 + wr * 64 + i * 16 + r0;
      float ml[4][4];
#pragma unroll
      for (int j = 0; j < 4; j++) {
        const int col = n0 + wc * 64 + j * 16 + fr;
#pragma unroll
        for (int r = 0; r < 4; r++)
          ml[j][r] = mk[(long)(row + r) * 2048 + col];   // 16 loads batched
      }
      float rs[4] = {0.f, 0.f, 0.f, 0.f};
#pragma unroll
      for (int j = 0; j < 4; j++) {
        const int col = n0 + wc * 64 + j * 16 + fr;
#pragma unroll
        for (int r = 0; r < 4; r++) {
          float e = __expf(acc[i][j][r] * scale + ml[j][r]);
          Pout[(long)(row + r) * ldc + col] = f2b(e);
          rs[r] += e;
        }
      }
#pragma unroll
      for (int r = 0; r < 4; r++) {
        float s = rs[r];
        s += __shfl_xor(s, 1); s += __shfl_xor(s, 2);
        s += __shfl_xor(s, 4); s += __shfl_xor(s, 8);
        if (fr == 0) atomicAdd(&rz[row + r], s);
      }
    }
  } else if (MODE == 0) {
#pragma unroll
    for (int i = 0; i < 4; i++) {
#pragma unroll
      for (int j = 0; j < 4; j++) {
        const int row = m0 + wr * 64 + i * 16 + r0;
        const int col = n0 + wc * 64 + j * 16 + fr;
        const float b = bias[col];
        if (col >= 2048) {
          u16x4 o = { f2b(acc[i][j][0] + b), f2b(acc[i][j][1] + b),
                      f2b(acc[i][j][2] + b), f2b(acc[i][j][3] + b) };
          *(u16x4*)(vtOut + (long)(col - 2048) * 8192 + row) = o;
        } else {
#pragma unroll
          for (int r = 0; r < 4; r++)
            ((u16*)C)[(long)(row + r) * ldc + col] = f2b(acc[i][j][r] + b);
        }
      }
    }
  } else {
    const float* lz = rsum + (long)z * 2048;
#pragma unroll
    for (int i = 0; i < 4; i++) {
      const int row = m0 + wr * 64 + i * 16 + r0;
      float inv[4];
#pragma unroll
      for (int r = 0; r < 4; r++) inv[r] = 1.0f / lz[row + r];
#pragma unroll
      for (int j = 0; j < 4; j++) {
        const int col = n0 + wc * 64 + j * 16 + fr;
#pragma unroll
        for (int r = 0; r < 4; r++)
          ((float*)C)[cbase + (long)(row + r) * ldc + col] = acc[i][j][r] * inv[r];
      }
    }
  }
}

// ---------------- persistent mega-kernel: prep | QKV | scores | PV ----------------
// 512 blocks x 256 threads (2 blocks/CU); phases separated by software grid barrier.
__global__ __launch_bounds__(256, 2) void fused(
    const float* __restrict__ x, const float* __restrict__ mask,
    const float* __restrict__ Wq, const float* __restrict__ Wk,
    const float* __restrict__ Wv,
    const float* __restrict__ bq, const float* __restrict__ bk,
    const float* __restrict__ bv,
    u16* xb, u16* wT, float* biasC,
    u16* QKV, u16* Vt, u16* Pp,
    float* rowsum, int* bar, float* out)
{
  __shared__ __align__(16) u16 lA[BM * BK];   // 16 KB
  __shared__ __align__(16) u16 lB[BN * BK];   // 16 KB
  const int t = threadIdx.x;

  // ---- phase A: prep (x->bf16, W transpose+cvt, bias concat, rowsum zero) ----
  for (int b = blockIdx.x; b < 8192 + 3072 + 44; b += NBLK) {
    if (b < 8192) {
      long i = ((long)b * 256 + t) * 4;
      float4 v = *(const float4*)(x + i);
      u16x4 o = { f2b(v.x), f2b(v.y), f2b(v.z), f2b(v.w) };
      *(u16x4*)(xb + i) = o;
    } else if (b < 8192 + 3072) {
      float* tl = (float*)lA;                  // [32][33] alias, 4.2 KB < 16 KB
      const int bb = b - 8192;
      const int zz = bb >> 10;
      const int tile = bb & 1023;
      const float* in = zz == 0 ? Wq : (zz == 1 ? Wk : Wv);
      u16* o = wT + (long)zz * 1024 * 1024;
      const int c0 = (tile & 31) * 32, r0 = (tile >> 5) * 32;
      const int tx = t & 31, ty = t >> 5;      // 32 x 8
      __syncthreads();                         // prior-iteration tile reads done
#pragma unroll
      for (int j = 0; j < 32; j += 8)
        tl[(ty + j) * 33 + tx] = in[(long)(r0 + ty + j) * 1024 + c0 + tx];
      __syncthreads();
#pragma unroll
      for (int j = 0; j < 32; j += 8)
        o[(long)(c0 + ty + j) * 1024 + r0 + tx] = f2b(tl[tx * 33 + ty + j]);
    } else {
      const int i = (b - 8192 - 3072) * 256 + t;
      if (i < 3072)
        biasC[i] = i < 1024 ? bq[i] : (i < 2048 ? bk[i - 1024] : bv[i - 2048]);
      else if (i < 3072 + 8192)
        rowsum[i - 3072] = 0.0f;
    }
  }
  gbar(&bar[0]);

  // ---- phase B: QKV — [8192,1024] x [3072,1024]^T, 1536 tiles = 3/block ----
  for (int idx = blockIdx.x; idx < 1536; idx += NBLK) {
    const int bx = idx % 24, by = idx / 24;
    gemm_tile<0>(lA, lB, xb, wT, QKV, Vt, biasC, nullptr, nullptr,
                 1024, 1024, 1024, 3072, by * BM, bx * BN, 0, 0, 1.0f);
  }
  gbar(&bar[1]);

  // ---- phase C: scores — P = exp(QK^T/32 + mask), 1024 tiles = 2/block ----
  for (int idx = blockIdx.x; idx < 1024; idx += NBLK) {
    const int zz = idx >> 8, rem = idx & 255;
    const int bx = rem & 15, by = rem >> 4;
    gemm_tile<2>(lA, lB,
                 QKV + (long)zz * 2048 * 3072, QKV + 1024 + (long)zz * 2048 * 3072,
                 Pp, nullptr, nullptr, rowsum, mask,
                 1024, 3072, 3072, 2048, by * BM, bx * BN,
                 (long)zz * 2048 * 2048, zz, 0.03125f);
  }
  gbar(&bar[2]);

  // ---- phase D: PV — out = (P V) / rowsum, 512 tiles = 1/block ----
  {
    const int idx = blockIdx.x;
    const int zz = idx >> 7, rem = idx & 127;
    const int bx = rem & 7, by = rem >> 3;
    gemm_tile<4>(lA, lB,
                 Pp + (long)zz * 2048 * 2048, Vt + (long)zz * 2048,
                 out, nullptr, nullptr, rowsum, nullptr,
                 2048, 2048, 8192, 1024, by * BM, bx * BN,
                 (long)zz * 2048 * 1024, zz, 1.0f);
  }
}

// ---------------- launch ----------------
extern "C" void kernel_launch(void* const* d_in, const int* in_sizes, int n_in,
                              void* d_out, int out_size, void* d_ws, size_t ws_size,
                              hipStream_t stream) {
  const float* x    = (const float*)d_in[0];   // [4,2048,1024]
  const float* mask = (const float*)d_in[1];   // [4,2048,2048]
  const float* Wq   = (const float*)d_in[2];
  const float* bq   = (const float*)d_in[3];
  const float* Wk   = (const float*)d_in[4];
  const float* bk   = (const float*)d_in[5];
  const float* Wv   = (const float*)d_in[6];
  const float* bv   = (const float*)d_in[7];
  float* out = (float*)d_out;

  char* w = (char*)d_ws;
  u16*   xb    = (u16*)(w);                 // x bf16      [8192,1024]
  u16*   wT    = (u16*)(w + 16777216);      // [Wq;Wk;Wv]^T bf16 [3072,1024]
  float* biasC = (float*)(w + 23068672);    // concat bias [3072]
  u16*   QKV   = (u16*)(w + 23081088);      // Q,K bf16    [8192,3072]
  u16*   Vt    = (u16*)(w + 73414016);      // V^T bf16    [1024,8192]
  u16*   Pp    = (u16*)(w + 90191232);      // P bf16      [4,2048,2048]
  float* rowsum= (float*)(w + 123745664);   // row sums    [8192]  (32 KB)
  int*   bar   = (int*)(w + 123778432);     // barrier counters [3]

  hipMemsetAsync(bar, 0, 3 * sizeof(int), stream);   // zero counters each replay
  fused<<<NBLK, 256, 0, stream>>>(x, mask, Wq, Wk, Wv, bq, bk, bv,
                                  xb, wT, biasC, QKV, Vt, Pp, rowsum, bar, out);
}

// Round 7
// 280.705 us; speedup vs baseline: 2.1711x; 2.1711x over previous
//
#include <hip/hip_runtime.h>
#include <hip/hip_bf16.h>
#include <stdint.h>

typedef unsigned short u16;
typedef __attribute__((ext_vector_type(4))) unsigned short u16x4;
typedef __attribute__((ext_vector_type(8))) short short8;
typedef __attribute__((ext_vector_type(4))) float f32x4;

__device__ inline u16 f2b(float f) {
  uint32_t u = __builtin_bit_cast(uint32_t, f);
  u += 0x7fffu + ((u >> 16) & 1u);   // RNE round to bf16
  return (u16)(u >> 16);
}

// ---------------- fused prep: x->bf16, W transpose+cvt, bias concat, rowsum zero --------
__global__ __launch_bounds__(256) void prep(
    const float* __restrict__ x, u16* __restrict__ xb,
    const float* __restrict__ Wq, const float* __restrict__ Wk,
    const float* __restrict__ Wv, u16* __restrict__ wT,
    const float* __restrict__ bq, const float* __restrict__ bk,
    const float* __restrict__ bv, float* __restrict__ biasC,
    float* __restrict__ rowsum) {
  __shared__ float tl[32][33];
  const int b = blockIdx.x;
  const int t = threadIdx.x;
  if (b < 8192) {
    long i = ((long)b * 256 + t) * 4;
    float4 v = *(const float4*)(x + i);
    u16x4 o = { f2b(v.x), f2b(v.y), f2b(v.z), f2b(v.w) };
    *(u16x4*)(xb + i) = o;
  } else if (b < 8192 + 3072) {
    const int bb = b - 8192;
    const int z = bb >> 10;            // 0..2 -> Wq/Wk/Wv
    const int tile = bb & 1023;
    const float* in = z == 0 ? Wq : (z == 1 ? Wk : Wv);
    u16* o = wT + (long)z * 1024 * 1024;
    const int c0 = (tile & 31) * 32, r0 = (tile >> 5) * 32;
    const int tx = t & 31, ty = t >> 5;   // 32 x 8
#pragma unroll
    for (int j = 0; j < 32; j += 8)
      tl[ty + j][tx] = in[(long)(r0 + ty + j) * 1024 + c0 + tx];
    __syncthreads();
#pragma unroll
    for (int j = 0; j < 32; j += 8)
      o[(long)(c0 + ty + j) * 1024 + r0 + tx] = f2b(tl[tx][ty + j]);
  } else {
    const int i = (b - 8192 - 3072) * 256 + t;
    if (i < 3072)
      biasC[i] = i < 1024 ? bq[i] : (i < 2048 ? bk[i - 1024] : bv[i - 2048]);
    else if (i < 3072 + 8192)
      rowsum[i - 3072] = 0.0f;
  }
}

#define BM 128
#define BN 128
#define BK 64

__device__ inline void load_lds16(const void* g, void* l) {
  __builtin_amdgcn_global_load_lds((const __attribute__((address_space(1))) void*)g,
                                   (__attribute__((address_space(3))) void*)l, 16, 0, 0);
}

// ---------------- 128x128 bt-GEMM, XOR-swizzled LDS, XCD-chunked block swizzle ----------
// 1D grid; logical tile s = (b&7)*swq + (b>>3)  (bijective: grid%8==0).
// Hardware round-robins blockIdx across the 8 XCDs, so each XCD receives a
// CONTIGUOUS run of logical tiles -> operand panels shared by neighboring tiles
// stay in that XCD's L2 instead of being re-fetched from L3/HBM per XCD.
// MODE 0: QKV epilogue (bias; cols>=2048 pre-transposed into vtOut)
// MODE 2: scores epilogue: P = exp(v*scale + mask) bf16; rowsum[row] += partials
// MODE 4: PV epilogue: fp32, v / rowsum[row]
template <int MODE>
__global__ __launch_bounds__(256, 2) void gemm_bt(
    const u16* __restrict__ A, const u16* __restrict__ Bt, void* __restrict__ C,
    u16* __restrict__ vtOut, const float* __restrict__ bias,
    float* __restrict__ rsum, const float* __restrict__ maskG,
    int K, int lda, int ldb, int ldc,
    long sA_, long sB_, long sC_, float scale,
    int swq, int tpz, int nx)
{
  // XCD-chunked bijective swizzle, then decode (z, by, bx)
  const int b = blockIdx.x;
  const int s = (b & 7) * swq + (b >> 3);
  const int z = s / tpz, rem = s % tpz;
  const int bx = rem % nx, by = rem / nx;

  A += z * sA_;
  Bt += z * sB_;
  const long cbase = z * sC_;

  __shared__ __align__(16) u16 lA[BM * BK];   // 16 KB
  __shared__ __align__(16) u16 lB[BN * BK];   // 16 KB

  const int t = threadIdx.x;
  const int lane = t & 63;
  const int wave = t >> 6;
  const int wr = wave >> 1, wc = wave & 1;
  const int m0 = by * BM, n0 = bx * BN;

  // Staging: LDS [128 rows][8 chunks of 8 u16]; slot s of row r holds global
  // chunk s ^ (r&7) -> conflict-free ds_read_b128; linear LDS dest (rule 21).
  const int srow = t >> 3;
  const int schunk = (t & 7) ^ (srow & 7);
  const u16* aS = A + (long)(m0 + srow) * lda + schunk * 8;
  const u16* bS = Bt + (long)(n0 + srow) * ldb + schunk * 8;

  f32x4 acc[4][4] = {};
  const int fr = lane & 15;
  const int q4 = lane >> 4;

  for (int k0 = 0; k0 < K; k0 += BK) {
    __syncthreads();                 // prior LDS reads done before overwrite
#pragma unroll
    for (int i = 0; i < 4; i++) {
      load_lds16(aS + k0 + (long)(i * 32) * lda, &lA[(i * 256 + t) * 8]);
      load_lds16(bS + k0 + (long)(i * 32) * ldb, &lB[(i * 256 + t) * 8]);
    }
    __syncthreads();                 // drain global_load_lds
#pragma unroll
    for (int kk = 0; kk < 2; kk++) {
      const int ch = kk * 4 + q4;
      short8 aF[4], bF[4];
#pragma unroll
      for (int i = 0; i < 4; i++) {
        int row = wr * 64 + i * 16 + fr;
        aF[i] = *(const short8*)&lA[row * BK + ((ch ^ (row & 7)) * 8)];
      }
#pragma unroll
      for (int j = 0; j < 4; j++) {
        int row = wc * 64 + j * 16 + fr;
        bF[j] = *(const short8*)&lB[row * BK + ((ch ^ (row & 7)) * 8)];
      }
#pragma unroll
      for (int i = 0; i < 4; i++)
#pragma unroll
        for (int j = 0; j < 4; j++)
          acc[i][j] = __builtin_amdgcn_mfma_f32_16x16x32_bf16(aF[i], bF[j], acc[i][j], 0, 0, 0);
    }
  }

  // epilogue: C/D layout col = lane&15, row = (lane>>4)*4 + r
  const int r0 = q4 * 4;
  if (MODE == 2) {
    const float* mk = maskG + (long)z * 2048 * 2048;
    u16* Pout = (u16*)C + cbase;
    float* rz = rsum + (long)z * 2048;
#pragma unroll
    for (int i = 0; i < 4; i++) {
      const int row = m0 + wr * 64 + i * 16 + r0;
      float ml[4][4];
#pragma unroll
      for (int j = 0; j < 4; j++) {
        const int col = n0 + wc * 64 + j * 16 + fr;
#pragma unroll
        for (int r = 0; r < 4; r++)
          ml[j][r] = mk[(long)(row + r) * 2048 + col];   // 16 loads batched
      }
      float rs[4] = {0.f, 0.f, 0.f, 0.f};
#pragma unroll
      for (int j = 0; j < 4; j++) {
        const int col = n0 + wc * 64 + j * 16 + fr;
#pragma unroll
        for (int r = 0; r < 4; r++) {
          float e = __expf(acc[i][j][r] * scale + ml[j][r]);
          Pout[(long)(row + r) * ldc + col] = f2b(e);
          rs[r] += e;
        }
      }
#pragma unroll
      for (int r = 0; r < 4; r++) {
        float s2 = rs[r];
        s2 += __shfl_xor(s2, 1); s2 += __shfl_xor(s2, 2);
        s2 += __shfl_xor(s2, 4); s2 += __shfl_xor(s2, 8);
        if (fr == 0) atomicAdd(&rz[row + r], s2);
      }
    }
  } else if (MODE == 0) {
#pragma unroll
    for (int i = 0; i < 4; i++) {
#pragma unroll
      for (int j = 0; j < 4; j++) {
        const int row = m0 + wr * 64 + i * 16 + r0;
        const int col = n0 + wc * 64 + j * 16 + fr;
        const float b2 = bias[col];
        if (col >= 2048) {
          u16x4 o = { f2b(acc[i][j][0] + b2), f2b(acc[i][j][1] + b2),
                      f2b(acc[i][j][2] + b2), f2b(acc[i][j][3] + b2) };
          *(u16x4*)(vtOut + (long)(col - 2048) * 8192 + row) = o;
        } else {
#pragma unroll
          for (int r = 0; r < 4; r++)
            ((u16*)C)[(long)(row + r) * ldc + col] = f2b(acc[i][j][r] + b2);
        }
      }
    }
  } else {
    const float* lz = rsum + (long)z * 2048;
#pragma unroll
    for (int i = 0; i < 4; i++) {
      const int row = m0 + wr * 64 + i * 16 + r0;
      float inv[4];
#pragma unroll
      for (int r = 0; r < 4; r++) inv[r] = 1.0f / lz[row + r];
#pragma unroll
      for (int j = 0; j < 4; j++) {
        const int col = n0 + wc * 64 + j * 16 + fr;
#pragma unroll
        for (int r = 0; r < 4; r++)
          ((float*)C)[cbase + (long)(row + r) * ldc + col] = acc[i][j][r] * inv[r];
      }
    }
  }
}

// ---------------- launch ----------------
extern "C" void kernel_launch(void* const* d_in, const int* in_sizes, int n_in,
                              void* d_out, int out_size, void* d_ws, size_t ws_size,
                              hipStream_t stream) {
  const float* x    = (const float*)d_in[0];   // [4,2048,1024]
  const float* mask = (const float*)d_in[1];   // [4,2048,2048]
  const float* Wq   = (const float*)d_in[2];
  const float* bq   = (const float*)d_in[3];
  const float* Wk   = (const float*)d_in[4];
  const float* bk   = (const float*)d_in[5];
  const float* Wv   = (const float*)d_in[6];
  const float* bv   = (const float*)d_in[7];
  float* out = (float*)d_out;

  char* w = (char*)d_ws;
  u16*   xb    = (u16*)(w);                 // x bf16      [8192,1024]
  u16*   wT    = (u16*)(w + 16777216);      // [Wq;Wk;Wv]^T bf16 [3072,1024]
  float* biasC = (float*)(w + 23068672);    // concat bias [3072]
  u16*   QKV   = (u16*)(w + 23081088);      // Q,K bf16    [8192,3072]
  u16*   Vt    = (u16*)(w + 73414016);      // V^T bf16    [1024,8192]
  u16*   Pp    = (u16*)(w + 90191232);      // P bf16      [4,2048,2048]
  float* rowsum= (float*)(w + 123745664);   // row sums    [8192]

  prep<<<8192 + 3072 + 44, 256, 0, stream>>>(x, xb, Wq, Wk, Wv, wT, bq, bk, bv, biasC, rowsum);

  // QKV: [8192,1024] x [3072,1024]^T -> Q,K + V^T.  1536 tiles, 24 per row.
  gemm_bt<0><<<1536, 256, 0, stream>>>(xb, wT, QKV, Vt, biasC, nullptr, nullptr,
      1024, 1024, 1024, 3072, 0, 0, 0, 1.0f,
      192, 1536, 24);

  // scores: P = exp(QK^T/32 + mask), rowsum in-epilogue.  1024 tiles = 4z x 16 x 16.
  gemm_bt<2><<<1024, 256, 0, stream>>>(QKV, QKV + 1024, Pp, nullptr, nullptr, rowsum, mask,
      1024, 3072, 3072, 2048,
      2048L * 3072, 2048L * 3072, 2048L * 2048, 0.03125f,
      128, 256, 16);

  // PV: out = (P V) / rowsum.  512 tiles = 4z x 16 x 8.
  gemm_bt<4><<<512, 256, 0, stream>>>(Pp, Vt, out, nullptr, nullptr, rowsum, nullptr,
      2048, 2048, 8192, 1024,
      2048L * 2048, 2048L, 2048L * 1024, 1.0f,
      64, 128, 8);
}